// Round 11
// baseline (83.029 us; speedup 1.0000x reference)
//
#include <hip/hip_runtime.h>

// ChamferLoss: B=4, N=M=8192, D=3, fp32. Scalar out.
// MFMA split-f16 (validated EXACT r6-r25): A = refs (LDS), B = queries (regs),
// in-lane min3 tree, 4-fused + 2x s_nop7 hazard pattern (r20).
// LEDGER: r0=77.4 | r17 fence=149 (NEVER per-block agent fences) | r18
// presplit=80.1 | r19 +gload_lds=82.8 | r20 4-fused @(256,4)=75.5 (BEST) |
// r21 rotate=77.4 | r22/r24 diags (mfma ~16us, fill ~41 FIXED, gaps ~15) |
// r23 SPAN1024=75.9 | r25 QT2@8w=80.1 | r26 mono-kernel=FAIL absmax=inf.
// r26 ROOT CAUSE: asm outputs "=v" WITHOUT early-clobber -> compiler
// allocated d0..d3 overlapping ar/bq inputs; MFMA #1 wrote d0 before
// MFMAs #2-4 read operands -> garbage -> 64 x 3e38 summed = inf. r13/r20
// "worked" only by allocation luck. RULE: multi-instr asm outputs MUST be
// "=&v".
// r27 (this): r26 + "=&v" on all MFMA outputs. Single delta. Mono-kernel:
// each block owns 64 queries (grid 128x4x2=1024 = 4 blk/CU, 16 waves/CU),
// iterates all 16 ref-chunks (LDS 2x16KB dbuf, T14 issue-early/write-late),
// block-local cross-wave min -> one atomicAdd(out)/block (fire-and-forget,
// no fences). Removes partial buffer, reduce kernel, one launch gap.
// Guards: pass but dur>=75.5 -> revert r20 permanently; fail -> revert r20.

#define BATCH   4
#define NPTS    8192
#define TPB     256
#define CHUNK   512                  // refs per LDS chunk
#define NCHUNK  (NPTS / CHUNK)       // 16
#define QBLK    64                   // queries per block
#define QBLKS   (NPTS / QBLK)        // 128
#define TPW     4                    // ref tiles per wave per chunk (16 / 4 waves)

typedef _Float16 h8   __attribute__((ext_vector_type(8)));
typedef float    f16v __attribute__((ext_vector_type(16)));

__device__ __forceinline__ void split16(float v, _Float16& hi, _Float16& lo) {
    hi = (_Float16)v;
    lo = (_Float16)(v - (float)hi);
}

__device__ __forceinline__ float tree16(const f16v& d) {
    float g0 = fminf(fminf(d[0],  d[1]),  d[2]);
    float g1 = fminf(fminf(d[3],  d[4]),  d[5]);
    float g2 = fminf(fminf(d[6],  d[7]),  d[8]);
    float g3 = fminf(fminf(d[9],  d[10]), d[11]);
    float g4 = fminf(fminf(d[12], d[13]), d[14]);
    float h0 = fminf(fminf(g0, g1), d[15]);
    float h1 = fminf(fminf(g2, g3), g4);
    return fminf(h0, h1);                 // caller folds cm -> min3 fuses
}

__global__ __launch_bounds__(TPB, 4) void chamfer_mono(const float* __restrict__ xg,
                                                       const float* __restrict__ yg,
                                                       float* __restrict__ out) {
    __shared__ h8    afrag[2][CHUNK * 2];     // 2 x 16 KB double buffer
    __shared__ float scm[4][2][32];           // cross-wave minima

    const int tid    = threadIdx.x;
    const int qblock = blockIdx.x;            // [0,128)
    const int b      = blockIdx.y;            // [0,4)
    const int dir    = blockIdx.z;            // [0,2)
    const int lane   = tid & 63, wave = tid >> 6;
    const int col    = lane & 31, hv = lane >> 5;

    const float* q = dir ? yg : xg;           // query side (cols, register B-frags)
    const float* r = dir ? xg : yg;           // reference side (rows, LDS A-frags)
    const float* rbase = r + (size_t)b * NPTS * 3;

    // ---- query B-frags: 2 col-tiles, shared by all waves ----
    h8 bq[2];
#pragma unroll
    for (int t = 0; t < 2; ++t) {
        const int qi = qblock * QBLK + t * 32 + col;
        const float* qp = q + ((size_t)b * NPTS + qi) * 3;
        float x0 = qp[0], x1 = qp[1], x2 = qp[2];
        _Float16 H0, L0, H1, L1, H2, L2, qnh, qnl;
        split16(-2.0f * x0, H0, L0);          // b-side: -2q, split AFTER scaling
        split16(-2.0f * x1, H1, L1);
        split16(-2.0f * x2, H2, L2);
        split16(fmaf(x0, x0, fmaf(x1, x1, x2 * x2)), qnh, qnl);
        h8 b0 = {H0, H1, H2, H0, H1, H2, L0, L1};                           // k0..7
        h8 b1 = {L2, (_Float16)1.0f, (_Float16)1.0f, qnh, qnl,
                 (_Float16)0.0f, (_Float16)0.0f, (_Float16)0.0f};           // k8..15
        bq[t] = hv ? b1 : b0;
    }

    // ---- stage chunk 0 (direct), de-interleaved layout (validated r6+) ----
#pragma unroll
    for (int i = 0; i < CHUNK / TPB; ++i) {
        const int p = tid + i * TPB;
        const float* s = rbase + (size_t)p * 3;
        float r0 = s[0], r1 = s[1], r2 = s[2];
        _Float16 h0, l0, h1, l1, h2, l2, rnh, rnl;
        split16(r0, h0, l0);
        split16(r1, h1, l1);
        split16(r2, h2, l2);
        split16(fmaf(r0, r0, fmaf(r1, r1, r2 * r2)), rnh, rnl);
        const int base = (p >> 5) * 64 + (p & 31);            // [tile][hv][row]
        afrag[0][base]      = (h8){h0, h1, h2, l0, l1, l2, h0, h1};
        afrag[0][base + 32] = (h8){h2, rnh, rnl, (_Float16)1.0f, (_Float16)1.0f,
                                   (_Float16)0.0f, (_Float16)0.0f, (_Float16)0.0f};
    }
    __syncthreads();

    float cm[2] = {3.0e38f, 3.0e38f};

    // ---- chunk loop: compute buf[cur] while reg-staging chunk c+1 ----
    for (int c = 0; c < NCHUNK; ++c) {
        const int cur = c & 1;

        // T14 issue-early: next chunk's coords to regs before compute
        float pc[CHUNK / TPB][3];
        if (c + 1 < NCHUNK) {
#pragma unroll
            for (int i = 0; i < CHUNK / TPB; ++i) {
                const int p = tid + i * TPB;
                const float* s = rbase + ((size_t)(c + 1) * CHUNK + p) * 3;
                pc[i][0] = s[0]; pc[i][1] = s[1]; pc[i][2] = s[2];
            }
        }

        // compute: this wave's 4 ref-tiles, as 2 pairs of r20's 4-fused group
#pragma unroll
        for (int pr = 0; pr < 2; ++pr) {
            const int rt = wave * TPW + pr * 2;
            const h8 ar0 = afrag[cur][rt * 64 + lane];        // conflict-free
            const h8 ar1 = afrag[cur][rt * 64 + 64 + lane];
            f16v d0, d1, d2, d3;
            asm("v_mfma_f32_32x32x16_f16 %0, %4, %6, 0\n\t"
                "v_mfma_f32_32x32x16_f16 %1, %4, %7, 0\n\t"
                "v_mfma_f32_32x32x16_f16 %2, %5, %6, 0\n\t"
                "v_mfma_f32_32x32x16_f16 %3, %5, %7, 0\n\t"
                "s_nop 7\n\t"
                "s_nop 7"
                : "=&v"(d0), "=&v"(d1), "=&v"(d2), "=&v"(d3)   // EARLY-CLOBBER:
                : "v"(ar0), "v"(ar1), "v"(bq[0]), "v"(bq[1])); // no in/out alias
            cm[0] = fminf(cm[0], tree16(d0));
            cm[1] = fminf(cm[1], tree16(d1));
            cm[0] = fminf(cm[0], tree16(d2));
            cm[1] = fminf(cm[1], tree16(d3));
        }

        // write-late: convert + store chunk c+1 into the other buffer
        if (c + 1 < NCHUNK) {
#pragma unroll
            for (int i = 0; i < CHUNK / TPB; ++i) {
                const int p = tid + i * TPB;
                float r0 = pc[i][0], r1 = pc[i][1], r2 = pc[i][2];
                _Float16 h0, l0, h1, l1, h2, l2, rnh, rnl;
                split16(r0, h0, l0);
                split16(r1, h1, l1);
                split16(r2, h2, l2);
                split16(fmaf(r0, r0, fmaf(r1, r1, r2 * r2)), rnh, rnl);
                const int base = (p >> 5) * 64 + (p & 31);
                afrag[cur ^ 1][base]      = (h8){h0, h1, h2, l0, l1, l2, h0, h1};
                afrag[cur ^ 1][base + 32] = (h8){h2, rnh, rnl, (_Float16)1.0f,
                                                 (_Float16)1.0f, (_Float16)0.0f,
                                                 (_Float16)0.0f, (_Float16)0.0f};
            }
        }
        __syncthreads();                      // buf[cur^1] ready; buf[cur] reusable
    }

    // ---- block-local finish: hv-fold -> cross-wave min -> sum -> one atomic ----
#pragma unroll
    for (int t = 0; t < 2; ++t) {
        cm[t] = fminf(cm[t], __shfl_xor(cm[t], 32, 64));      // merge row halves
        if (hv == 0) scm[wave][t][col] = cm[t];
    }
    __syncthreads();
    if (tid < 64) {
        const int t = tid >> 5, cc = tid & 31;
        float v = fminf(fminf(scm[0][t][cc], scm[1][t][cc]),
                        fminf(scm[2][t][cc], scm[3][t][cc]));  // min over waves' refs
#pragma unroll
        for (int off = 32; off > 0; off >>= 1)
            v += __shfl_down(v, off, 64);                      // sum 64 query minima
        if (tid == 0)
            atomicAdd(out, v * (1.0f / (float)(BATCH * NPTS)));
    }
}

extern "C" void kernel_launch(void* const* d_in, const int* in_sizes, int n_in,
                              void* d_out, int out_size, void* d_ws, size_t ws_size,
                              hipStream_t stream) {
    const float* x = (const float*)d_in[0];
    const float* y = (const float*)d_in[1];
    float* out = (float*)d_out;
    (void)d_ws; (void)ws_size;

    hipMemsetAsync(out, 0, sizeof(float), stream);   // stream-ordered, capture-safe
    chamfer_mono<<<dim3(QBLKS, BATCH, 2), TPB, 0, stream>>>(x, y, out);
}

// Round 12
// 77.695 us; speedup vs baseline: 1.0687x; 1.0687x over previous
//
#include <hip/hip_runtime.h>

// ChamferLoss: B=4, N=M=8192, D=3, fp32. Scalar out.
// FINAL (r28 = byte-exact r20 restore, the measured optimum).
// MFMA split-f16: A = refs (LDS, de-interleaved), B = queries (regs),
// in-lane min3 tree, VGPR-dest asm MFMA, 4-fused issue group + 2x s_nop7
// hazard tail, __launch_bounds__(256,4) = 4-wave band (acc d0-d3 = 64 regs).
// LEDGER: r0(2+2,8w)=77.4 | r17 fused-reduce fences=149 (per-block agent
// fences = buffer_wbl2/inv TCC storm - NEVER) | r18 presplit=80.1 | r19
// presplit+gload_lds=82.8 | r20 THIS=75.5 BEST | r21 rotated pipeline=77.4 |
// r22/r24 z-diags (mfma=16.1us linear; fill=41us FIXED incl. when ws unused;
// boundaries ~16us) | r23 SPAN1024=75.9 | r25 QT2@8w=80.1 | r26 mono=FAIL
// (asm outputs MUST be "=&v" early-clobber in multi-instr blocks) | r27
// mono fixed=83.0 (staging redundancy x8 > reduce+boundary savings).
// r24 COUNTERS (the book-closing measurement): MfmaUtil 42% = exact pipe
// demand; pure VALU ~28% (min3 IS fused); Occ 46% = VGPR-band limit;
// LDS_CONFLICT 0; HBM 1.3%. ~30% issue idle not recoverable by schedule
// (r21), occupancy (r25), tile size (r23), or structure (r27).
// Budget: fill 41 (harness, untouchable) + mfma 16.1 + reduce 2 + launch
// boundaries ~16. Controllable part ~15% above dispatch-overhead floor.

#define BATCH   4
#define NPTS    8192
#define TPB     256
#define CSLICE  512                  // ref points per block (LDS slice)
#define QT      4                    // query tiles (32 cols) per wave
#define QBLK    (4 * QT * 32)        // 512 queries per block
#define MT      (CSLICE / 32)        // 16 ref tiles per slice
#define SLICES  (NPTS / CSLICE)      // 16
#define QBLKS   (NPTS / QBLK)        // 16

typedef _Float16 h8   __attribute__((ext_vector_type(8)));
typedef float    f16v __attribute__((ext_vector_type(16)));

__device__ __forceinline__ void split16(float v, _Float16& hi, _Float16& lo) {
    hi = (_Float16)v;
    lo = (_Float16)(v - (float)hi);
}

__device__ __forceinline__ float tree16(const f16v& d) {
    float g0 = fminf(fminf(d[0],  d[1]),  d[2]);
    float g1 = fminf(fminf(d[3],  d[4]),  d[5]);
    float g2 = fminf(fminf(d[6],  d[7]),  d[8]);
    float g3 = fminf(fminf(d[9],  d[10]), d[11]);
    float g4 = fminf(fminf(d[12], d[13]), d[14]);
    float h0 = fminf(fminf(g0, g1), d[15]);
    float h1 = fminf(fminf(g2, g3), g4);
    return fminf(h0, h1);
}

__global__ __launch_bounds__(TPB, 4) void chamfer_mfma(const float* __restrict__ xg,
                                                       const float* __restrict__ yg,
                                                       float* __restrict__ partial,
                                                       float* __restrict__ out) {
    __shared__ h8 afrag[CSLICE * 2];          // 16 KB, de-interleaved (conflict-free)

    const int tid    = threadIdx.x;
    const int qblock = blockIdx.x;            // [0,16)
    const int slice  = blockIdx.y & (SLICES - 1);
    const int b      = blockIdx.y >> 4;       // SLICES == 16
    const int dir    = blockIdx.z;
    const int lane   = tid & 63, wave = tid >> 6;
    const int col    = lane & 31, hv = lane >> 5;

    if (tid == 0) out[0] = 0.0f;              // benign identical-value race;
                                              // reduce runs after via stream order
    const float* q = dir ? yg : xg;           // query side (cols, register B-frags)
    const float* r = dir ? xg : yg;           // reference side (rows, LDS A-frags)

    // ---- stage ref A-frags: 2 points per thread, de-interleaved layout ----
    const float* rbase = r + ((size_t)b * NPTS + slice * CSLICE) * 3;
#pragma unroll
    for (int i = 0; i < CSLICE / TPB; ++i) {
        const int p = tid + i * TPB;
        float r0 = rbase[p * 3 + 0], r1 = rbase[p * 3 + 1], r2 = rbase[p * 3 + 2];
        _Float16 h0, l0, h1, l1, h2, l2, rnh, rnl;
        split16(r0, h0, l0);                  // a-side: RAW coords
        split16(r1, h1, l1);
        split16(r2, h2, l2);
        split16(fmaf(r0, r0, fmaf(r1, r1, r2 * r2)), rnh, rnl);
        const int base = (p >> 5) * 64 + (p & 31);            // [tile][hv][row]
        afrag[base]      = (h8){h0, h1, h2, l0, l1, l2, h0, h1};            // k0..7
        afrag[base + 32] = (h8){h2, rnh, rnl, (_Float16)1.0f, (_Float16)1.0f,
                                (_Float16)0.0f, (_Float16)0.0f, (_Float16)0.0f}; // k8..15
    }

    // ---- query B-frags: QT col-tiles per wave, resident in registers ----
    h8 bq[QT];
#pragma unroll
    for (int t = 0; t < QT; ++t) {
        const int qi = qblock * QBLK + (wave * QT + t) * 32 + col;
        const float* qp = q + ((size_t)b * NPTS + qi) * 3;
        float x0 = qp[0], x1 = qp[1], x2 = qp[2];
        _Float16 H0, L0, H1, L1, H2, L2, qnh, qnl;
        split16(-2.0f * x0, H0, L0);          // b-side: -2q, split AFTER scaling
        split16(-2.0f * x1, H1, L1);
        split16(-2.0f * x2, H2, L2);
        split16(fmaf(x0, x0, fmaf(x1, x1, x2 * x2)), qnh, qnl);
        h8 b0 = {H0, H1, H2, H0, H1, H2, L0, L1};                           // k0..7
        h8 b1 = {L2, (_Float16)1.0f, (_Float16)1.0f, qnh, qnl,
                 (_Float16)0.0f, (_Float16)0.0f, (_Float16)0.0f};           // k8..15
        bq[t] = hv ? b1 : b0;
    }
    __syncthreads();

    float cm[QT];
#pragma unroll
    for (int t = 0; t < QT; ++t) cm[t] = 3.0e38f;

    // ---- main loop: 1 A-frag read -> 4 MFMAs back-to-back, then 4 trees ----
    for (int mt = 0; mt < MT; ++mt) {
        const h8 ar = afrag[mt * 64 + lane];   // contiguous 16B/lane, conflict-free
        f16v d0, d1, d2, d3;
        asm("v_mfma_f32_32x32x16_f16 %0, %4, %5, 0\n\t"
            "v_mfma_f32_32x32x16_f16 %1, %4, %6, 0\n\t"
            "v_mfma_f32_32x32x16_f16 %2, %4, %7, 0\n\t"
            "v_mfma_f32_32x32x16_f16 %3, %4, %8, 0\n\t"
            "s_nop 7\n\t"
            "s_nop 7"
            : "=v"(d0), "=v"(d1), "=v"(d2), "=v"(d3)
            : "v"(ar), "v"(bq[0]), "v"(bq[1]), "v"(bq[2]), "v"(bq[3]));
        cm[0] = fminf(cm[0], tree16(d0));
        cm[1] = fminf(cm[1], tree16(d1));
        cm[2] = fminf(cm[2], tree16(d2));
        cm[3] = fminf(cm[3], tree16(d3));
    }

    // ---- epilogue: one xor32 per accumulator, coalesced stores ----
    float* pp = partial + ((size_t)(dir * BATCH + b) * SLICES + slice) * NPTS
                        + qblock * QBLK;
#pragma unroll
    for (int t = 0; t < QT; ++t) {
        cm[t] = fminf(cm[t], __shfl_xor(cm[t], 32, 64));   // hv-partner rows
        if (hv == 0)
            pp[(wave * QT + t) * 32 + col] = cm[t];        // 32 lanes, 128B coalesced
    }
}

__global__ __launch_bounds__(TPB) void chamfer_reduce(const float* __restrict__ partial,
                                                      float* __restrict__ out) {
    const int tid = threadIdx.x;
    const int g   = blockIdx.x * TPB + tid;   // [0, 2*BATCH*NPTS)
    const int db  = g >> 13;                  // (dir*BATCH + b)
    const int n   = g & (NPTS - 1);

    const float* p = partial + (size_t)db * SLICES * NPTS + n;
    float v = 3.0e38f;
#pragma unroll
    for (int s = 0; s < SLICES; ++s)
        v = fminf(v, p[(size_t)s * NPTS]);    // coalesced across threads

    float w = v;
#pragma unroll
    for (int off = 32; off > 0; off >>= 1)
        w += __shfl_down(w, off, 64);
    __shared__ float ss[TPB / 64];
    if ((tid & 63) == 0) ss[tid >> 6] = w;
    __syncthreads();
    if (tid == 0)
        atomicAdd(out, (ss[0] + ss[1] + ss[2] + ss[3]) * (1.0f / (float)(BATCH * NPTS)));
}

extern "C" void kernel_launch(void* const* d_in, const int* in_sizes, int n_in,
                              void* d_out, int out_size, void* d_ws, size_t ws_size,
                              hipStream_t stream) {
    const float* x = (const float*)d_in[0];
    const float* y = (const float*)d_in[1];
    float* out = (float*)d_out;
    float* partial = (float*)d_ws;            // 2*4*16*8192*4 = 4 MB

    chamfer_mfma<<<dim3(QBLKS, BATCH * SLICES, 2), TPB, 0, stream>>>(x, y, partial, out);
    chamfer_reduce<<<dim3(2 * BATCH * NPTS / TPB), TPB, 0, stream>>>(partial, out);
}